// Round 10
// baseline (184.383 us; speedup 1.0000x reference)
//
#include <hip/hip_runtime.h>
#include <math.h>

typedef __bf16 bf16x8 __attribute__((ext_vector_type(8)));
typedef __bf16 bf16x4 __attribute__((ext_vector_type(4)));
typedef float  f32x4  __attribute__((ext_vector_type(4)));

namespace {
constexpr int L_ = 512, D_ = 512, NF = 11;
constexpr long WE = (long)L_ * L_;   // 262144 elems, one 512x512 plane
constexpr long NE = 8 * WE;          // 2097152 elems, B*L*D
constexpr long CPL = 512L * 1024;    // concatenated plane (512 rows x 1024)
constexpr float NEGV = -1.0e9f;
constexpr float INV_TEMP = 0.044194173824159216f; // 1/sqrt(512)
}

typedef __attribute__((address_space(1))) void gv_t;
typedef __attribute__((address_space(3))) void lv_t;

__device__ __forceinline__ void async_cp16(const void* g, void* l) {
  __builtin_amdgcn_global_load_lds((gv_t*)g, (lv_t*)l, 16, 0, 0);
}

__device__ __forceinline__ bf16x8 cvt2(float4 a0, float4 a1) {
  bf16x8 f;
  f[0] = (__bf16)a0.x; f[1] = (__bf16)a0.y; f[2] = (__bf16)a0.z; f[3] = (__bf16)a0.w;
  f[4] = (__bf16)a1.x; f[5] = (__bf16)a1.y; f[6] = (__bf16)a1.z; f[7] = (__bf16)a1.w;
  return f;
}

// ======== m97-exact 128x128 NT core: BK=32, cp16 width-16, bf16 operands ========
__device__ __forceinline__ void core_m97(const __bf16* __restrict__ A,
                                         const __bf16* __restrict__ B, int K,
                                         int m0, int n0,
                                         __bf16* sA, __bf16* sB, f32x4 (&acc)[4][4])
{
  const int tid = threadIdx.x;
  const int wave = tid >> 6, lane = tid & 63;
  const int srow = tid >> 2, scol = (tid & 3) * 8;
  const int quad = lane >> 4, l16 = lane & 15;
  const int wm = (wave >> 1) * 64, wn = (wave & 1) * 64;
  const __bf16* ga = A + (long)(m0 + srow) * K + scol;
  const __bf16* gb = B + (long)(n0 + srow) * K + scol;
  __bf16* dA = sA + srow * 32 + scol;
  __bf16* dB = sB + srow * 32 + scol;
  const __bf16* rA = sA + (wm + l16) * 32 + quad * 8;
  const __bf16* rB = sB + (wn + l16) * 32 + quad * 8;
  for (int k0 = 0; k0 < K; k0 += 32) {
    __syncthreads();
    async_cp16(ga + k0,               dA);
    async_cp16(ga + (long)64 * K + k0, dA + 64 * 32);
    async_cp16(gb + k0,               dB);
    async_cp16(gb + (long)64 * K + k0, dB + 64 * 32);
    __syncthreads();
    bf16x8 af[4], bfr[4];
    #pragma unroll
    for (int i = 0; i < 4; ++i) af[i]  = *(const bf16x8*)(rA + i * 16 * 32);
    #pragma unroll
    for (int j = 0; j < 4; ++j) bfr[j] = *(const bf16x8*)(rB + j * 16 * 32);
    #pragma unroll
    for (int i = 0; i < 4; ++i)
      #pragma unroll
      for (int j = 0; j < 4; ++j)
        acc[i][j] = __builtin_amdgcn_mfma_f32_16x16x32_bf16(af[i], bfr[j], acc[i][j], 0, 0, 0);
  }
}

// ======== proj: m97 core, XCD-swizzled. z: 0=qp 1=kp 2=qfT 3=kfT 4=vp ========
__global__ __launch_bounds__(256)
void proj_kernel(const __bf16* __restrict__ qkvb, const __bf16* __restrict__ Wb,
                 __bf16* __restrict__ qcat, __bf16* __restrict__ kcat,
                 __bf16* __restrict__ qfkfT, __bf16* __restrict__ vpb)
{
  __shared__ __align__(16) __bf16 sA[128 * 32];
  __shared__ __align__(16) __bf16 sB[128 * 32];
  // swizzle: co-locate all n-tiles (and all z) of one A-row-group on one XCD
  const int fid = blockIdx.x + 4 * blockIdx.y + 128 * blockIdx.z; // 0..639
  const int xcd = fid & 7, w = fid >> 3;
  const int z = w >> 4, r = w & 15;
  const int m0 = ((r >> 2) * 8 + xcd) * 128;  // m-tile 0..31
  const int n0 = (r & 3) * 128;
  const __bf16* A = qkvb + (long)((z == 4) ? 2 : (z & 1)) * NE;
  const __bf16* B = Wb + (long)z * WE;

  f32x4 acc[4][4];
  #pragma unroll
  for (int i = 0; i < 4; ++i)
    #pragma unroll
    for (int j = 0; j < 4; ++j) acc[i][j] = 0.0f;
  core_m97(A, B, 512, m0, n0, sA, sB, acc);

  const int wave = threadIdx.x >> 6, lane = threadIdx.x & 63;
  const int quad = lane >> 4, l16 = lane & 15;
  const int wm = (wave >> 1) * 64, wn = (wave & 1) * 64;
  #pragma unroll
  for (int i = 0; i < 4; ++i) {
    const int mb = m0 + wm + i * 16 + quad * 4;
    #pragma unroll
    for (int j = 0; j < 4; ++j) {
      const int nn = n0 + wn + j * 16 + l16;
      f32x4 c = acc[i][j];
      if (z < 2) {
        __bf16* C = (z == 0) ? qcat : kcat;
        #pragma unroll
        for (int r2 = 0; r2 < 4; ++r2)
          C[(long)(mb + r2) * 1024 + nn] = (__bf16)c[r2];
      } else if (z == 4) {
        #pragma unroll
        for (int r2 = 0; r2 < 4; ++r2)
          vpb[(long)(mb + r2) * 512 + nn] = (__bf16)c[r2];
      } else {
        __bf16* T = qfkfT + (long)(z - 2) * NE;
        const long bb = (long)(mb >> 9) << 18;
        const int l = mb & 511;
        bf16x4 pk;
        pk[0] = (__bf16)c[0]; pk[1] = (__bf16)c[1];
        pk[2] = (__bf16)c[2]; pk[3] = (__bf16)c[3];
        *(bf16x4*)(T + bb + (long)nn * 512 + l) = pk;
      }
    }
  }
}

// mega2 (m97 core): z 0..7 qf2->qcat[:,512:], 8..15 kf2->kcat[:,512:], 16..23 vp2T=NT(Wfc,vp[b])
__global__ __launch_bounds__(256)
void mega2_kernel(const __bf16* __restrict__ featb, const __bf16* __restrict__ qfkfT,
                  const __bf16* __restrict__ Wfcb, const __bf16* __restrict__ vpb,
                  __bf16* __restrict__ qcat, __bf16* __restrict__ kcat,
                  __bf16* __restrict__ vp2T)
{
  __shared__ __align__(16) __bf16 sA[128 * 32];
  __shared__ __align__(16) __bf16 sB[128 * 32];
  const int z = blockIdx.z;
  const __bf16 *A, *B;
  __bf16* C;
  int ldc;
  if (z < 16) {
    const int b = z & 7, s = z >> 3;
    A = featb + (long)b * WE;
    B = qfkfT + (long)s * NE + (long)b * WE;
    C = (s ? kcat : qcat) + (long)b * CPL + 512;
    ldc = 1024;
  } else {
    const int b = z - 16;
    A = Wfcb;
    B = vpb + (long)b * WE;
    C = vp2T + (long)b * WE;
    ldc = 512;
  }
  const int m0 = blockIdx.y * 128, n0 = blockIdx.x * 128;
  f32x4 acc[4][4];
  #pragma unroll
  for (int i = 0; i < 4; ++i)
    #pragma unroll
    for (int j = 0; j < 4; ++j) acc[i][j] = 0.0f;
  core_m97(A, B, 512, m0, n0, sA, sB, acc);

  const int wave = threadIdx.x >> 6, lane = threadIdx.x & 63;
  const int quad = lane >> 4, l16 = lane & 15;
  const int wm = (wave >> 1) * 64, wn = (wave & 1) * 64;
  #pragma unroll
  for (int i = 0; i < 4; ++i) {
    const int mb = m0 + wm + i * 16 + quad * 4;
    #pragma unroll
    for (int j = 0; j < 4; ++j) {
      const int nn = n0 + wn + j * 16 + l16;
      f32x4 c = acc[i][j];
      #pragma unroll
      for (int r2 = 0; r2 < 4; ++r2)
        C[(long)(mb + r2) * ldc + nn] = (__bf16)c[r2];
    }
  }
}

// scores: 64x128 cp16 core, K=1024. attn = tanh(mask(./temp)) -> fp32. grid (4,8,8)
__global__ __launch_bounds__(256)
void scores_kernel(const __bf16* __restrict__ qcat, const __bf16* __restrict__ kcat,
                   const int* __restrict__ lens, float* __restrict__ attnf)
{
  __shared__ __align__(16) __bf16 sA[64 * 32];
  __shared__ __align__(16) __bf16 sB[128 * 32];
  const int b = blockIdx.z;
  const int len = lens[b];
  const __bf16* A = qcat + (long)b * CPL;
  const __bf16* B = kcat + (long)b * CPL;
  const int m0 = blockIdx.y * 64, n0 = blockIdx.x * 128;
  const int tid = threadIdx.x;
  const int wave = tid >> 6, lane = tid & 63;
  const int srow = tid >> 2, scol = (tid & 3) * 8;
  const int quad = lane >> 4, l16 = lane & 15;
  const int wm = (wave >> 1) * 32, wn = (wave & 1) * 64;
  const __bf16* ga = A + (long)(m0 + srow) * 1024 + scol;
  const __bf16* gb = B + (long)(n0 + srow) * 1024 + scol;
  __bf16* dA = sA + srow * 32 + scol;
  __bf16* dB = sB + srow * 32 + scol;
  const __bf16* rA = sA + (wm + l16) * 32 + quad * 8;
  const __bf16* rB = sB + (wn + l16) * 32 + quad * 8;

  f32x4 acc[2][4];
  #pragma unroll
  for (int i = 0; i < 2; ++i)
    #pragma unroll
    for (int j = 0; j < 4; ++j) acc[i][j] = 0.0f;

  for (int k0 = 0; k0 < 1024; k0 += 32) {
    __syncthreads();
    async_cp16(ga + k0,                  dA);
    async_cp16(gb + k0,                  dB);
    async_cp16(gb + (long)64 * 1024 + k0, dB + 64 * 32);
    __syncthreads();
    bf16x8 af[2], bfr[4];
    #pragma unroll
    for (int i = 0; i < 2; ++i) af[i]  = *(const bf16x8*)(rA + i * 16 * 32);
    #pragma unroll
    for (int j = 0; j < 4; ++j) bfr[j] = *(const bf16x8*)(rB + j * 16 * 32);
    #pragma unroll
    for (int i = 0; i < 2; ++i)
      #pragma unroll
      for (int j = 0; j < 4; ++j)
        acc[i][j] = __builtin_amdgcn_mfma_f32_16x16x32_bf16(af[i], bfr[j], acc[i][j], 0, 0, 0);
  }

  const long off = (long)b * WE;
  #pragma unroll
  for (int i = 0; i < 2; ++i) {
    const int mb = m0 + wm + i * 16 + quad * 4;
    #pragma unroll
    for (int j = 0; j < 4; ++j) {
      const int nn = n0 + wn + j * 16 + l16;
      f32x4 c = acc[i][j];
      #pragma unroll
      for (int r2 = 0; r2 < 4; ++r2) {
        float vv = c[r2] * INV_TEMP;
        vv = (nn < len) ? tanhf(vv) : 0.0f;
        attnf[off + (long)(mb + r2) * 512 + nn] = vv;
      }
    }
  }
}

// av2: out2[b] = attn[b] @ vp2[b]; A = attn fp32 (in-reg cvt), 64x64, grid (8,8,8)
__global__ __launch_bounds__(256)
void av2_kernel(const float* __restrict__ attnf, const __bf16* __restrict__ vp2T,
                float* __restrict__ out2)
{
  __shared__ __align__(16) __bf16 sA[2 * 64 * 32];
  __shared__ __align__(16) __bf16 sB[2 * 64 * 32];
  const int b = blockIdx.z;
  const int m0 = blockIdx.y * 64, n0 = blockIdx.x * 64;
  const int tid = threadIdx.x;
  const int wave = tid >> 6, lane = tid & 63;
  const int srow = tid >> 2, scol = (tid & 3) * 8;
  const int quad = lane >> 4, l16 = lane & 15;
  const int wm = (wave >> 1) * 32, wn = (wave & 1) * 32;
  const float*  gAf = attnf + (long)b * WE + (long)(m0 + srow) * 512 + scol;
  const __bf16* gB  = vp2T + (long)b * WE + (long)(n0 + srow) * 512 + scol;
  __bf16* dA = sA + srow * 32 + scol;
  __bf16* dB = sB + srow * 32 + scol;

  f32x4 acc[2][2];
  #pragma unroll
  for (int i = 0; i < 2; ++i)
    #pragma unroll
    for (int j = 0; j < 2; ++j) acc[i][j] = 0.0f;

  float4 fa[2][2];
  bf16x8 rb[2];
  fa[0][0] = *(const float4*)(gAf);      fa[0][1] = *(const float4*)(gAf + 4);
  fa[1][0] = *(const float4*)(gAf + 32); fa[1][1] = *(const float4*)(gAf + 36);
  rb[0] = *(const bf16x8*)(gB);
  rb[1] = *(const bf16x8*)(gB + 32);

  for (int k0 = 0; k0 < 512; k0 += 64) {
    __syncthreads();
    *(bf16x8*)(dA)        = cvt2(fa[0][0], fa[0][1]);
    *(bf16x8*)(dA + 2048) = cvt2(fa[1][0], fa[1][1]);
    *(bf16x8*)(dB)        = rb[0];
    *(bf16x8*)(dB + 2048) = rb[1];
    __syncthreads();
    if (k0 + 64 < 512) {
      const int kn = k0 + 64;
      fa[0][0] = *(const float4*)(gAf + kn);      fa[0][1] = *(const float4*)(gAf + kn + 4);
      fa[1][0] = *(const float4*)(gAf + kn + 32); fa[1][1] = *(const float4*)(gAf + kn + 36);
      rb[0] = *(const bf16x8*)(gB + kn);
      rb[1] = *(const bf16x8*)(gB + kn + 32);
    }
    #pragma unroll
    for (int p = 0; p < 2; ++p) {
      bf16x8 af[2], bfr[2];
      #pragma unroll
      for (int i = 0; i < 2; ++i)
        af[i]  = *(const bf16x8*)(sA + p * 2048 + (wm + i * 16 + l16) * 32 + quad * 8);
      #pragma unroll
      for (int j = 0; j < 2; ++j)
        bfr[j] = *(const bf16x8*)(sB + p * 2048 + (wn + j * 16 + l16) * 32 + quad * 8);
      #pragma unroll
      for (int i = 0; i < 2; ++i)
        #pragma unroll
        for (int j = 0; j < 2; ++j)
          acc[i][j] = __builtin_amdgcn_mfma_f32_16x16x32_bf16(af[i], bfr[j], acc[i][j], 0, 0, 0);
    }
  }

  const long off = (long)b * WE;
  #pragma unroll
  for (int i = 0; i < 2; ++i) {
    const int mb = m0 + wm + i * 16 + quad * 4;
    #pragma unroll
    for (int j = 0; j < 2; ++j) {
      const int nn = n0 + wn + j * 16 + l16;
      f32x4 c = acc[i][j];
      #pragma unroll
      for (int r2 = 0; r2 < 4; ++r2)
        out2[off + (long)(mb + r2) * 512 + nn] = c[r2];
    }
  }
}

// ======== cvtfeat: y=0 qkv+weights fp32->bf16, y=1 feature softmax ========
__global__ __launch_bounds__(256)
void cvtfeat_kernel(const float* __restrict__ q, const float* __restrict__ k,
                    const float* __restrict__ v,
                    const float* __restrict__ Wq, const float* __restrict__ Wk,
                    const float* __restrict__ Wqf, const float* __restrict__ Wkf,
                    const float* __restrict__ Wv, const float* __restrict__ Wfc,
                    __bf16* __restrict__ qkvb, __bf16* __restrict__ Wb,
                    const float* __restrict__ x, const float* __restrict__ imp,
                    const int* __restrict__ lens, __bf16* __restrict__ featb)
{
  __shared__ float xfs[L_ * NF]; // 22.5 KB (feat path)
  const int tid = threadIdx.x;
  const int wave = tid >> 6, lane = tid & 63;
  if (blockIdx.y == 0) {
    const int gtid = blockIdx.x * 256 + tid; // 0..65535
    const float* s3[3] = {q, k, v};
    #pragma unroll
    for (int a = 0; a < 3; ++a) {
      const float* s = s3[a];
      __bf16* d = qkvb + (long)a * NE;
      for (long i = gtid; i < (NE >> 2); i += 65536) {
        float4 vv = *(const float4*)(s + i * 4);
        bf16x4 o;
        o[0] = (__bf16)vv.x; o[1] = (__bf16)vv.y; o[2] = (__bf16)vv.z; o[3] = (__bf16)vv.w;
        *(bf16x4*)(d + i * 4) = o;
      }
    }
    const float* w6[6] = {Wq, Wk, Wqf, Wkf, Wv, Wfc};
    #pragma unroll
    for (int a = 0; a < 6; ++a) {
      const float* s = w6[a];
      __bf16* d = Wb + (long)a * WE;
      long i = gtid; // WE/4 = 65536 exactly
      float4 vv = *(const float4*)(s + i * 4);
      bf16x4 o;
      o[0] = (__bf16)vv.x; o[1] = (__bf16)vv.y; o[2] = (__bf16)vv.z; o[3] = (__bf16)vv.w;
      *(bf16x4*)(d + i * 4) = o;
    }
  } else {
    if (blockIdx.x >= 128) return;
    const int b = blockIdx.x >> 4;
    const int i0 = (blockIdx.x & 15) * 32;
    for (int idx = tid; idx < L_ * NF; idx += 256) {
      int j = idx / NF, f = idx - j * NF;
      xfs[idx] = x[((long)b * L_ + j) * D_ + f];
    }
    float im[NF];
    #pragma unroll
    for (int f = 0; f < NF; ++f) im[f] = imp[f];
    const int len = lens[b];
    __syncthreads();
    for (int r = 0; r < 8; ++r) {
      const int i = i0 + wave * 8 + r;
      float xi[NF];
      #pragma unroll
      for (int f = 0; f < NF; ++f) xi[f] = xfs[i * NF + f];
      float l[8];
      float m = -INFINITY;
      #pragma unroll
      for (int t = 0; t < 8; ++t) {
        int j = lane + t * 64;
        float s = 0.f;
        #pragma unroll
        for (int f = 0; f < NF; ++f) s = fmaf(fabsf(xi[f] - xfs[j * NF + f]), im[f], s);
        s = (j < len) ? s : NEGV;
        l[t] = s;
        m = fmaxf(m, s);
      }
      #pragma unroll
      for (int o = 32; o >= 1; o >>= 1) m = fmaxf(m, __shfl_xor(m, o));
      float ssum = 0.f;
      #pragma unroll
      for (int t = 0; t < 8; ++t) { l[t] = expf(l[t] - m); ssum += l[t]; }
      #pragma unroll
      for (int o = 32; o >= 1; o >>= 1) ssum += __shfl_xor(ssum, o);
      float inv = 1.0f / ssum;
      #pragma unroll
      for (int t = 0; t < 8; ++t)
        featb[((long)b * L_ + i) * L_ + lane + t * 64] = (__bf16)(l[t] * inv);
    }
  }
}

// ---------------- LayerNorm: 4 rows per block ----------------
__global__ __launch_bounds__(256) void ln_kernel(const float* __restrict__ xin, const float* __restrict__ res,
                                                 const float* __restrict__ gamma, const float* __restrict__ beta,
                                                 float* __restrict__ out)
{
    const int wave = threadIdx.x >> 6, lane = threadIdx.x & 63;
    const long row = blockIdx.x * 4 + wave;
    float v[8];
    float s = 0.f, ss = 0.f;
    #pragma unroll
    for (int t = 0; t < 8; ++t) {
        float u = xin[row * D_ + lane + t * 64] + res[row * D_ + lane + t * 64];
        v[t] = u; s += u; ss = fmaf(u, u, ss);
    }
    #pragma unroll
    for (int o = 32; o >= 1; o >>= 1) { s += __shfl_xor(s, o); ss += __shfl_xor(ss, o); }
    const float mu = s * (1.0f / D_);
    const float var = ss * (1.0f / D_) - mu * mu;
    const float inv = 1.0f / sqrtf(var + 1e-6f);
    #pragma unroll
    for (int t = 0; t < 8; ++t) {
        int d = lane + t * 64;
        out[row * D_ + d] = (v[t] - mu) * inv * gamma[d] + beta[d];
    }
}

extern "C" void kernel_launch(void* const* d_in, const int* in_sizes, int n_in,
                              void* d_out, int out_size, void* d_ws, size_t ws_size,
                              hipStream_t stream) {
    const float* q     = (const float*)d_in[0];
    const float* k     = (const float*)d_in[1];
    const float* v     = (const float*)d_in[2];
    const float* x     = (const float*)d_in[3];
    const int*   lens  = (const int*)d_in[4];
    const float* Wq    = (const float*)d_in[5];
    const float* Wk    = (const float*)d_in[6];
    const float* Wv    = (const float*)d_in[7];
    const float* Wqf   = (const float*)d_in[8];
    const float* Wkf   = (const float*)d_in[9];
    const float* Wfc   = (const float*)d_in[10];
    const float* imp   = (const float*)d_in[11];
    const float* gamma = (const float*)d_in[12];
    const float* beta  = (const float*)d_in[13];

    constexpr long MB = 1 << 20;
    char* w = (char*)d_ws;
    __bf16* qkvb  = (__bf16*)(w);            //  0..12MB : q,k,v bf16
    __bf16* Wb    = (__bf16*)(w + 12 * MB);  // 12..15MB : Wq,Wk,Wqf,Wkf,Wv,Wfc bf16
    __bf16* qfkfT = (__bf16*)(w + 15 * MB);  // 15..23MB : qfT,kfT
    __bf16* vpb   = (__bf16*)(w + 23 * MB);  // 23..27MB : vp
    __bf16* vp2T  = (__bf16*)(w + 27 * MB);  // 27..31MB : vp2T
    __bf16* qcat  = (__bf16*)(w + 31 * MB);  // 31..39MB : [qp | qf2] K=1024
    __bf16* kcat  = (__bf16*)(w + 39 * MB);  // 39..47MB : [kp | kf2]
    float*  out2  = (float*)(w + 47 * MB);   // 47..55MB : pre-LN fp32
    __bf16* featb = (__bf16*)(w + 55 * MB);  // 55..59MB : feat_attn bf16

    float*  outp  = (float*)d_out;           // output 0 [B,L,D]
    float*  attnf = outp + NE;               // output 1 [B,L,L]

    // 1) qkv+weights -> bf16 (y=0) + feature softmax (y=1)
    cvtfeat_kernel<<<dim3(256, 2), 256, 0, stream>>>(q, k, v, Wq, Wk, Wqf, Wkf, Wv, Wfc,
                                                     qkvb, Wb, x, imp, lens, featb);

    // 2) 5 projections, m97 core, XCD-swizzled (640 blocks)
    proj_kernel<<<dim3(4, 32, 5), 256, 0, stream>>>(qkvb, Wb, qcat, kcat, qfkfT, vpb);

    // 3) qf2,kf2 -> cat right halves + vp2T = Wfc.vp^T, m97 core (384 blocks)
    mega2_kernel<<<dim3(4, 4, 24), 256, 0, stream>>>(featb, qfkfT, Wb + 5 * WE, vpb,
                                                     qcat, kcat, vp2T);

    // 4) attn = tanh(mask(qcat.kcat^T / temp)), K=1024 (256 blocks)
    scores_kernel<<<dim3(4, 8, 8), 256, 0, stream>>>(qcat, kcat, lens, attnf);

    // 5) out2 = attn @ vp2 (512 blocks)
    av2_kernel<<<dim3(8, 8, 8), 256, 0, stream>>>(attnf, vp2T, out2);

    // 6) LayerNorm(out2 + q)
    ln_kernel<<<1024, 256, 0, stream>>>(out2, q, gamma, beta, outp);
}

// Round 11
// 178.591 us; speedup vs baseline: 1.0324x; 1.0324x over previous
//
#include <hip/hip_runtime.h>
#include <math.h>

typedef __bf16 bf16x8 __attribute__((ext_vector_type(8)));
typedef __bf16 bf16x4 __attribute__((ext_vector_type(4)));
typedef float  f32x4  __attribute__((ext_vector_type(4)));

namespace {
constexpr int L_ = 512, D_ = 512, NF = 11;
constexpr long WE = (long)L_ * L_;   // 262144 elems, one 512x512 plane
constexpr long NE = 8 * WE;          // 2097152 elems, B*L*D
constexpr long CPL = 512L * 1024;    // concatenated plane (512 rows x 1024)
constexpr float NEGV = -1.0e9f;
constexpr float INV_TEMP = 0.044194173824159216f; // 1/sqrt(512)
}

typedef __attribute__((address_space(1))) void gv_t;
typedef __attribute__((address_space(3))) void lv_t;

__device__ __forceinline__ void async_cp16(const void* g, void* l) {
  __builtin_amdgcn_global_load_lds((gv_t*)g, (lv_t*)l, 16, 0, 0);
}

__device__ __forceinline__ bf16x8 cvt2(float4 a0, float4 a1) {
  bf16x8 f;
  f[0] = (__bf16)a0.x; f[1] = (__bf16)a0.y; f[2] = (__bf16)a0.z; f[3] = (__bf16)a0.w;
  f[4] = (__bf16)a1.x; f[5] = (__bf16)a1.y; f[6] = (__bf16)a1.z; f[7] = (__bf16)a1.w;
  return f;
}

// ======== 64x128 NT core, BK=64 (two 32-col panels), VGPR-prefetch staging ========
template<bool AF32, bool BF32>
__device__ __forceinline__ void core128(const void* Av, const void* Bv,
                                        int K, int m0, int n0,
                                        __bf16* sA, __bf16* sB, f32x4 (&acc)[2][4])
{
  const int tid = threadIdx.x;
  const int wave = tid >> 6, lane = tid & 63;
  const int srow = tid >> 2, scol = (tid & 3) * 8;
  const int quad = lane >> 4, l16 = lane & 15;
  const int wm = (wave >> 1) * 32, wn = (wave & 1) * 64;
  const float*  gAf = (const float*)Av  + (long)(m0 + srow) * K + scol;
  const __bf16* gAb = (const __bf16*)Av + (long)(m0 + srow) * K + scol;
  const float*  gBf = (const float*)Bv  + (long)(n0 + srow) * K + scol;
  const __bf16* gBb = (const __bf16*)Bv + (long)(n0 + srow) * K + scol;
  __bf16* dA = sA + srow * 32 + scol;   // sA: [2][64][32]  panel stride 2048
  __bf16* dB = sB + srow * 32 + scol;   // sB: [2][128][32] panel stride 4096

  float4 fa[2][2]; bf16x8 ba[2];
  float4 fb[4][2]; bf16x8 rb[4];
  const long bofs[4] = {0, 32, (long)64 * K, (long)64 * K + 32};

  if (AF32) {
    fa[0][0] = *(const float4*)(gAf);      fa[0][1] = *(const float4*)(gAf + 4);
    fa[1][0] = *(const float4*)(gAf + 32); fa[1][1] = *(const float4*)(gAf + 36);
  } else {
    ba[0] = *(const bf16x8*)(gAb);
    ba[1] = *(const bf16x8*)(gAb + 32);
  }
  #pragma unroll
  for (int c = 0; c < 4; ++c) {
    if (BF32) { fb[c][0] = *(const float4*)(gBf + bofs[c]); fb[c][1] = *(const float4*)(gBf + bofs[c] + 4); }
    else      { rb[c] = *(const bf16x8*)(gBb + bofs[c]); }
  }

  const int dBo[4] = {0, 4096, 64 * 32, 4096 + 64 * 32};
  for (int k0 = 0; k0 < K; k0 += 64) {
    __syncthreads();
    {
      bf16x8 wa0, wa1;
      if (AF32) { wa0 = cvt2(fa[0][0], fa[0][1]); wa1 = cvt2(fa[1][0], fa[1][1]); }
      else      { wa0 = ba[0]; wa1 = ba[1]; }
      *(bf16x8*)(dA)        = wa0;
      *(bf16x8*)(dA + 2048) = wa1;
      #pragma unroll
      for (int c = 0; c < 4; ++c) {
        bf16x8 wb;
        if (BF32) wb = cvt2(fb[c][0], fb[c][1]);
        else      wb = rb[c];
        *(bf16x8*)(dB + dBo[c]) = wb;
      }
    }
    __syncthreads();
    if (k0 + 64 < K) {
      const int kn = k0 + 64;
      if (AF32) {
        fa[0][0] = *(const float4*)(gAf + kn);      fa[0][1] = *(const float4*)(gAf + kn + 4);
        fa[1][0] = *(const float4*)(gAf + kn + 32); fa[1][1] = *(const float4*)(gAf + kn + 36);
      } else {
        ba[0] = *(const bf16x8*)(gAb + kn);
        ba[1] = *(const bf16x8*)(gAb + kn + 32);
      }
      #pragma unroll
      for (int c = 0; c < 4; ++c) {
        if (BF32) { fb[c][0] = *(const float4*)(gBf + kn + bofs[c]); fb[c][1] = *(const float4*)(gBf + kn + bofs[c] + 4); }
        else      { rb[c] = *(const bf16x8*)(gBb + kn + bofs[c]); }
      }
    }
    #pragma unroll
    for (int p = 0; p < 2; ++p) {
      bf16x8 af[2], bfr[4];
      #pragma unroll
      for (int i = 0; i < 2; ++i)
        af[i]  = *(const bf16x8*)(sA + p * 2048 + (wm + i * 16 + l16) * 32 + quad * 8);
      #pragma unroll
      for (int j = 0; j < 4; ++j)
        bfr[j] = *(const bf16x8*)(sB + p * 4096 + (wn + j * 16 + l16) * 32 + quad * 8);
      #pragma unroll
      for (int i = 0; i < 2; ++i)
        #pragma unroll
        for (int j = 0; j < 4; ++j)
          acc[i][j] = __builtin_amdgcn_mfma_f32_16x16x32_bf16(af[i], bfr[j], acc[i][j], 0, 0, 0);
    }
  }
}

// ======== 64x64 NT core, BK=64 panels, bf16 operands (scores) ========
__device__ __forceinline__ void core64(const __bf16* __restrict__ A, const __bf16* __restrict__ B,
                                       int K, int m0, int n0,
                                       __bf16* sA, __bf16* sB, f32x4 (&acc)[2][2])
{
  const int tid = threadIdx.x;
  const int wave = tid >> 6, lane = tid & 63;
  const int srow = tid >> 2, scol = (tid & 3) * 8;
  const int quad = lane >> 4, l16 = lane & 15;
  const int wm = (wave >> 1) * 32, wn = (wave & 1) * 32;
  const __bf16* gA = A + (long)(m0 + srow) * K + scol;
  const __bf16* gB = B + (long)(n0 + srow) * K + scol;
  __bf16* dA = sA + srow * 32 + scol;
  __bf16* dB = sB + srow * 32 + scol;

  bf16x8 ra[2], rb[2];
  ra[0] = *(const bf16x8*)(gA);
  ra[1] = *(const bf16x8*)(gA + 32);
  rb[0] = *(const bf16x8*)(gB);
  rb[1] = *(const bf16x8*)(gB + 32);

  for (int k0 = 0; k0 < K; k0 += 64) {
    __syncthreads();
    *(bf16x8*)(dA)        = ra[0];
    *(bf16x8*)(dA + 2048) = ra[1];
    *(bf16x8*)(dB)        = rb[0];
    *(bf16x8*)(dB + 2048) = rb[1];
    __syncthreads();
    if (k0 + 64 < K) {
      const int kn = k0 + 64;
      ra[0] = *(const bf16x8*)(gA + kn);
      ra[1] = *(const bf16x8*)(gA + kn + 32);
      rb[0] = *(const bf16x8*)(gB + kn);
      rb[1] = *(const bf16x8*)(gB + kn + 32);
    }
    #pragma unroll
    for (int p = 0; p < 2; ++p) {
      bf16x8 af[2], bfr[2];
      #pragma unroll
      for (int i = 0; i < 2; ++i)
        af[i]  = *(const bf16x8*)(sA + p * 2048 + (wm + i * 16 + l16) * 32 + quad * 8);
      #pragma unroll
      for (int j = 0; j < 2; ++j)
        bfr[j] = *(const bf16x8*)(sB + p * 2048 + (wn + j * 16 + l16) * 32 + quad * 8);
      #pragma unroll
      for (int i = 0; i < 2; ++i)
        #pragma unroll
        for (int j = 0; j < 2; ++j)
          acc[i][j] = __builtin_amdgcn_mfma_f32_16x16x32_bf16(af[i], bfr[j], acc[i][j], 0, 0, 0);
    }
  }
}

// ======== projfeat: flat grid, XCD-swizzled. fid<1280 GEMM, fid>=1280 feat ========
// GEMM work w=(z,m,n): xcd = m&7 so all n-tiles/z-pairs sharing A rows co-locate per XCD.
__global__ __launch_bounds__(256)
void projfeat_kernel(const float* __restrict__ q, const float* __restrict__ k,
                     const float* __restrict__ v,
                     const float* __restrict__ Wq, const float* __restrict__ Wk,
                     const float* __restrict__ Wqf, const float* __restrict__ Wkf,
                     const float* __restrict__ Wv,
                     const float* __restrict__ x, const float* __restrict__ imp,
                     const int* __restrict__ lens,
                     __bf16* __restrict__ qcat, __bf16* __restrict__ kcat,
                     __bf16* __restrict__ qfkfT, __bf16* __restrict__ vpb,
                     __bf16* __restrict__ featb)
{
  __shared__ __align__(16) char smem[24576];
  const int fid = blockIdx.x;
  const int tid = threadIdx.x;
  const int wave = tid >> 6, lane = tid & 63;

  if (fid < 1280) {
    const int xcd = fid & 7, g = fid >> 3;       // g in [0,160)
    const int n = g & 3, mh = (g >> 2) & 7, z = g >> 5;
    const int m0 = (mh * 8 + xcd) * 64;          // m-tile in [0,64)
    const int n0 = n * 128;
    __bf16* sA = (__bf16*)smem;
    __bf16* sB = sA + 2 * 64 * 32;
    const float* As[5] = {q, k, q, k, v};
    const float* Bs[5] = {Wq, Wk, Wqf, Wkf, Wv};
    f32x4 acc[2][4];
    #pragma unroll
    for (int i = 0; i < 2; ++i)
      #pragma unroll
      for (int j = 0; j < 4; ++j) acc[i][j] = 0.0f;
    core128<true, true>(As[z], Bs[z], 512, m0, n0, sA, sB, acc);

    const int quad = lane >> 4, l16 = lane & 15;
    const int wm = (wave >> 1) * 32, wn = (wave & 1) * 64;
    #pragma unroll
    for (int i = 0; i < 2; ++i) {
      const int mb = m0 + wm + i * 16 + quad * 4;
      #pragma unroll
      for (int j = 0; j < 4; ++j) {
        const int nn = n0 + wn + j * 16 + l16;
        f32x4 c = acc[i][j];
        if (z < 2) {
          __bf16* C = (z == 0) ? qcat : kcat;
          #pragma unroll
          for (int r2 = 0; r2 < 4; ++r2)
            C[(long)(mb + r2) * 1024 + nn] = (__bf16)c[r2];
        } else if (z == 4) {
          #pragma unroll
          for (int r2 = 0; r2 < 4; ++r2)
            vpb[(long)(mb + r2) * 512 + nn] = (__bf16)c[r2];
        } else {
          __bf16* T = qfkfT + (long)(z - 2) * NE;
          const long bb = (long)(mb >> 9) << 18;
          const int l = mb & 511;
          bf16x4 pk;
          pk[0] = (__bf16)c[0]; pk[1] = (__bf16)c[1];
          pk[2] = (__bf16)c[2]; pk[3] = (__bf16)c[3];
          *(bf16x4*)(T + bb + (long)nn * 512 + l) = pk;
        }
      }
    }
  } else {
    const int flat = fid - 1280;                 // 0..127
    float* xfs = (float*)smem;                   // 22.5 KB
    const int b = flat >> 4;
    const int i0 = (flat & 15) * 32;
    for (int idx = tid; idx < L_ * NF; idx += 256) {
      int j = idx / NF, f = idx - j * NF;
      xfs[idx] = x[((long)b * L_ + j) * D_ + f];
    }
    float im[NF];
    #pragma unroll
    for (int f = 0; f < NF; ++f) im[f] = imp[f];
    const int len = lens[b];
    __syncthreads();
    for (int r = 0; r < 8; ++r) {
      const int i = i0 + wave * 8 + r;
      float xi[NF];
      #pragma unroll
      for (int f = 0; f < NF; ++f) xi[f] = xfs[i * NF + f];
      float l[8];
      float m = -INFINITY;
      #pragma unroll
      for (int t = 0; t < 8; ++t) {
        int j = lane + t * 64;
        float s = 0.f;
        #pragma unroll
        for (int f = 0; f < NF; ++f) s = fmaf(fabsf(xi[f] - xfs[j * NF + f]), im[f], s);
        s = (j < len) ? s : NEGV;
        l[t] = s;
        m = fmaxf(m, s);
      }
      #pragma unroll
      for (int o = 32; o >= 1; o >>= 1) m = fmaxf(m, __shfl_xor(m, o));
      float ssum = 0.f;
      #pragma unroll
      for (int t = 0; t < 8; ++t) { l[t] = expf(l[t] - m); ssum += l[t]; }
      #pragma unroll
      for (int o = 32; o >= 1; o >>= 1) ssum += __shfl_xor(ssum, o);
      float inv = 1.0f / ssum;
      #pragma unroll
      for (int t = 0; t < 8; ++t)
        featb[((long)b * L_ + i) * L_ + lane + t * 64] = (__bf16)(l[t] * inv);
    }
  }
}

// mega2: z 0..7 qf2 -> qcat[:,512:], z 8..15 kf2 -> kcat[:,512:], z 16..23 vp2T = NT(Wfc, vp[b])
__global__ __launch_bounds__(256)
void mega2_kernel(const __bf16* __restrict__ featb, const __bf16* __restrict__ qfkfT,
                  const float* __restrict__ Wfc, const __bf16* __restrict__ vpb,
                  __bf16* __restrict__ qcat, __bf16* __restrict__ kcat,
                  __bf16* __restrict__ vp2T)
{
  __shared__ __align__(16) __bf16 sA[2 * 64 * 32];
  __shared__ __align__(16) __bf16 sB[2 * 128 * 32];
  const int z = blockIdx.z;
  const int m0 = blockIdx.y * 64, n0 = blockIdx.x * 128;
  f32x4 acc[2][4];
  #pragma unroll
  for (int i = 0; i < 2; ++i)
    #pragma unroll
    for (int j = 0; j < 4; ++j) acc[i][j] = 0.0f;

  __bf16* C;
  int ldc;
  if (z < 16) {
    const int b = z & 7, s = z >> 3;
    const __bf16* A = featb + (long)b * WE;
    const __bf16* B = qfkfT + (long)s * NE + (long)b * WE;
    C = (s ? kcat : qcat) + (long)b * CPL + 512;
    ldc = 1024;
    core128<false, false>(A, B, 512, m0, n0, sA, sB, acc);
  } else {
    const int b = z - 16;
    const __bf16* B = vpb + (long)b * WE;
    C = vp2T + (long)b * WE;
    ldc = 512;
    core128<true, false>(Wfc, B, 512, m0, n0, sA, sB, acc);
  }

  const int wave = threadIdx.x >> 6, lane = threadIdx.x & 63;
  const int quad = lane >> 4, l16 = lane & 15;
  const int wm = (wave >> 1) * 32, wn = (wave & 1) * 64;
  #pragma unroll
  for (int i = 0; i < 2; ++i) {
    const int mb = m0 + wm + i * 16 + quad * 4;
    #pragma unroll
    for (int j = 0; j < 4; ++j) {
      const int nn = n0 + wn + j * 16 + l16;
      f32x4 c = acc[i][j];
      #pragma unroll
      for (int r2 = 0; r2 < 4; ++r2)
        C[(long)(mb + r2) * ldc + nn] = (__bf16)c[r2];
    }
  }
}

// scores: attn = tanh(mask(./temp)), K=1024, 64x64 tiles; writes fp32 (out1) + bf16 (for av2)
__global__ __launch_bounds__(256)
void scores_kernel(const __bf16* __restrict__ qcat, const __bf16* __restrict__ kcat,
                   const int* __restrict__ lens, float* __restrict__ attnf,
                   __bf16* __restrict__ attnb)
{
  __shared__ __align__(16) __bf16 sA[2 * 64 * 32];
  __shared__ __align__(16) __bf16 sB[2 * 64 * 32];
  const int b = blockIdx.z;
  const int len = lens[b];
  const int m0 = blockIdx.y * 64, n0 = blockIdx.x * 64;
  f32x4 acc[2][2];
  #pragma unroll
  for (int i = 0; i < 2; ++i)
    #pragma unroll
    for (int j = 0; j < 2; ++j) acc[i][j] = 0.0f;
  core64(qcat + (long)b * CPL, kcat + (long)b * CPL, 1024, m0, n0, sA, sB, acc);

  const long off = (long)b * WE;
  const int wave = threadIdx.x >> 6, lane = threadIdx.x & 63;
  const int quad = lane >> 4, l16 = lane & 15;
  const int wm = (wave >> 1) * 32, wn = (wave & 1) * 32;
  #pragma unroll
  for (int i = 0; i < 2; ++i) {
    const int mb = m0 + wm + i * 16 + quad * 4;
    #pragma unroll
    for (int j = 0; j < 2; ++j) {
      const int nn = n0 + wn + j * 16 + l16;
      f32x4 c = acc[i][j];
      #pragma unroll
      for (int r2 = 0; r2 < 4; ++r2) {
        float vv = c[r2] * INV_TEMP;
        vv = (nn < len) ? tanhf(vv) : 0.0f;
        attnf[off + (long)(mb + r2) * 512 + nn] = vv;
        attnb[off + (long)(mb + r2) * 512 + nn] = (__bf16)vv;
      }
    }
  }
}

// ======== av2ln: out = LN(attn@vp2 + q); block = 16 rows x full 512 cols ========
// grid (32, 1, 8): bx = m-tile, bz = b. Wave w owns cols [w*128, w*128+128).
__global__ __launch_bounds__(256)
void av2ln_kernel(const __bf16* __restrict__ attnb, const __bf16* __restrict__ vp2T,
                  const float* __restrict__ q, const float* __restrict__ gamma,
                  const float* __restrict__ beta, float* __restrict__ outp)
{
  __shared__ __align__(16) __bf16 sA[16 * 32];     // 1 KB
  __shared__ __align__(16) __bf16 sB[512 * 32];    // 32 KB
  __shared__ float lnbuf[4][16][2];                // per-wave row partials
  __shared__ float lnmv[16][2];                    // (mu, inv) per row
  const int b = blockIdx.z;
  const int m0 = blockIdx.x * 16;
  const int tid = threadIdx.x;
  const int wave = tid >> 6, lane = tid & 63;
  const int quad = lane >> 4, l16 = lane & 15;
  const long aoff = (long)b * WE;

  f32x4 acc[8];
  #pragma unroll
  for (int j = 0; j < 8; ++j) acc[j] = 0.0f;

  for (int k0 = 0; k0 < 512; k0 += 32) {
    __syncthreads();
    if (wave == 0) { // A: 16 rows x 32 cols; LDS dest = base + lane*16 (linear)
      const int ar = lane >> 2, ac = (lane & 3) * 8;
      async_cp16(attnb + aoff + (long)(m0 + ar) * 512 + k0 + ac, (char*)sA + lane * 16);
    }
    #pragma unroll
    for (int it = 0; it < 8; ++it) { // B: 512 rows x 32 cols, chunk = it*4+wave (16 rows each)
      const int chunk = it * 4 + wave;
      const int d = chunk * 16 + (lane >> 2), c = (lane & 3) * 8;
      async_cp16(vp2T + aoff + (long)d * 512 + k0 + c, (char*)sB + chunk * 1024 + lane * 16);
    }
    __syncthreads();
    bf16x8 af = *(const bf16x8*)(sA + l16 * 32 + quad * 8);
    #pragma unroll
    for (int j = 0; j < 8; ++j) {
      bf16x8 bfr = *(const bf16x8*)(sB + (wave * 128 + j * 16 + l16) * 32 + quad * 8);
      acc[j] = __builtin_amdgcn_mfma_f32_16x16x32_bf16(af, bfr, acc[j], 0, 0, 0);
    }
  }

  // add residual, row sums (rows quad*4+r for this lane's quad)
  float uval[8][4];
  float s[4] = {0.f, 0.f, 0.f, 0.f}, ss[4] = {0.f, 0.f, 0.f, 0.f};
  #pragma unroll
  for (int r = 0; r < 4; ++r) {
    const long row = (long)b * 512 + m0 + quad * 4 + r;
    #pragma unroll
    for (int j = 0; j < 8; ++j) {
      const int col = wave * 128 + j * 16 + l16;
      float u = acc[j][r] + q[row * 512 + col];
      uval[j][r] = u;
      s[r] += u;
      ss[r] = fmaf(u, u, ss[r]);
    }
  }
  #pragma unroll
  for (int o = 1; o <= 8; o <<= 1) {   // reduce across the 16 lanes of this quad
    #pragma unroll
    for (int r = 0; r < 4; ++r) { s[r] += __shfl_xor(s[r], o); ss[r] += __shfl_xor(ss[r], o); }
  }
  if (l16 == 0) {
    #pragma unroll
    for (int r = 0; r < 4; ++r) {
      lnbuf[wave][quad * 4 + r][0] = s[r];
      lnbuf[wave][quad * 4 + r][1] = ss[r];
    }
  }
  __syncthreads();
  if (tid < 16) {
    float S = 0.f, SS = 0.f;
    #pragma unroll
    for (int w = 0; w < 4; ++w) { S += lnbuf[w][tid][0]; SS += lnbuf[w][tid][1]; }
    const float mu = S * (1.0f / 512.0f);
    const float var = SS * (1.0f / 512.0f) - mu * mu;
    lnmv[tid][0] = mu;
    lnmv[tid][1] = 1.0f / sqrtf(var + 1e-6f);
  }
  __syncthreads();
  #pragma unroll
  for (int r = 0; r < 4; ++r) {
    const int rr = quad * 4 + r;
    const float mu = lnmv[rr][0], inv = lnmv[rr][1];
    const long row = (long)b * 512 + m0 + rr;
    #pragma unroll
    for (int j = 0; j < 8; ++j) {
      const int col = wave * 128 + j * 16 + l16;
      outp[row * 512 + col] = (uval[j][r] - mu) * inv * gamma[col] + beta[col];
    }
  }
}

extern "C" void kernel_launch(void* const* d_in, const int* in_sizes, int n_in,
                              void* d_out, int out_size, void* d_ws, size_t ws_size,
                              hipStream_t stream) {
    const float* q     = (const float*)d_in[0];
    const float* k     = (const float*)d_in[1];
    const float* v     = (const float*)d_in[2];
    const float* x     = (const float*)d_in[3];
    const int*   lens  = (const int*)d_in[4];
    const float* Wq    = (const float*)d_in[5];
    const float* Wk    = (const float*)d_in[6];
    const float* Wv    = (const float*)d_in[7];
    const float* Wqf   = (const float*)d_in[8];
    const float* Wkf   = (const float*)d_in[9];
    const float* Wfc   = (const float*)d_in[10];
    const float* imp   = (const float*)d_in[11];
    const float* gamma = (const float*)d_in[12];
    const float* beta  = (const float*)d_in[13];

    constexpr long MB = 1 << 20;
    char* w = (char*)d_ws;
    __bf16* qfkfT = (__bf16*)(w);            //  0.. 8MB : qfT,kfT
    __bf16* vpb   = (__bf16*)(w + 8 * MB);   //  8..12MB : vp
    __bf16* vp2T  = (__bf16*)(w + 12 * MB);  // 12..16MB : vp2T
    __bf16* qcat  = (__bf16*)(w + 16 * MB);  // 16..24MB : [qp | qf2] K=1024
    __bf16* kcat  = (__bf16*)(w + 24 * MB);  // 24..32MB : [kp | kf2]
    __bf16* featb = (__bf16*)(w + 32 * MB);  // 32..36MB : feat_attn bf16
    __bf16* attnb = (__bf16*)(w + 36 * MB);  // 36..40MB : attn bf16

    float*  outp  = (float*)d_out;           // output 0 [B,L,D]
    float*  attnf = outp + NE;               // output 1 [B,L,L]

    // 1) 5 projections (fp32 A,B in-register cvt; XCD-swizzled) + feature softmax
    projfeat_kernel<<<dim3(1408), 256, 0, stream>>>(q, k, v, Wq, Wk, Wqf, Wkf, Wv,
                                                    x, imp, lens,
                                                    qcat, kcat, qfkfT, vpb, featb);

    // 2) qf2,kf2 -> cat right halves + vp2T = Wfc.vp^T (768 blocks)
    mega2_kernel<<<dim3(4, 8, 24), 256, 0, stream>>>(featb, qfkfT, Wfc, vpb,
                                                     qcat, kcat, vp2T);

    // 3) attn = tanh(mask(qcat.kcat^T / temp)), K=1024 (512 blocks, 64x64)
    scores_kernel<<<dim3(8, 8, 8), 256, 0, stream>>>(qcat, kcat, lens, attnf, attnb);

    // 4) out = LN(attn @ vp2 + q) fused (256 blocks, full-row)
    av2ln_kernel<<<dim3(32, 1, 8), 256, 0, stream>>>(attnb, vp2T, q, gamma, beta, outp);
}